// Round 3
// baseline (308.972 us; speedup 1.0000x reference)
//
#include <hip/hip_runtime.h>
#include <hip/hip_bf16.h>

typedef __attribute__((ext_vector_type(4))) float f32x4;
typedef __attribute__((ext_vector_type(8))) __bf16 bf16x8;

__device__ __forceinline__ unsigned short f2bf(float f) {
    union { float f; unsigned u; } x; x.f = f;
    unsigned r = x.u + 0x7fffu + ((x.u >> 16) & 1u);
    return (unsigned short)(r >> 16);
}
__device__ __forceinline__ float bf2f(unsigned short b) {
    union { unsigned u; float f; } x; x.u = ((unsigned)b) << 16;
    return x.f;
}

__device__ __forceinline__ void gload16(const void* g, void* l) {
    __builtin_amdgcn_global_load_lds(
        (const __attribute__((address_space(1))) unsigned int*)g,
        (__attribute__((address_space(3))) unsigned int*)l,
        16, 0, 0);
}

template <int N> __device__ __forceinline__ void vm_wait();
template <> __device__ __forceinline__ void vm_wait<0>() { asm volatile("s_waitcnt vmcnt(0)" ::: "memory"); }
template <> __device__ __forceinline__ void vm_wait<2>() { asm volatile("s_waitcnt vmcnt(2)" ::: "memory"); }
template <> __device__ __forceinline__ void vm_wait<4>() { asm volatile("s_waitcnt vmcnt(4)" ::: "memory"); }

// ---------------- elementwise convert (f32 -> bf16, with scale) ----------------
__global__ void k_convert_scale(const float* __restrict__ in, unsigned short* __restrict__ out,
                                int n4, float scale) {
    int i = blockIdx.x * 256 + threadIdx.x;
    if (i >= n4) return;
    float4 v = reinterpret_cast<const float4*>(in)[i];
    union { unsigned short u[4]; uint2 q; } o;
    o.u[0] = f2bf(v.x * scale);
    o.u[1] = f2bf(v.y * scale);
    o.u[2] = f2bf(v.z * scale);
    o.u[3] = f2bf(v.w * scale);
    reinterpret_cast<uint2*>(out)[i] = o.q;
}

// ---------------- transpose 4x [1024x1024] f32 -> bf16 (W^T) ----------------
__global__ void k_transpose_w(const float* __restrict__ W0, const float* __restrict__ W1,
                              const float* __restrict__ W2, const float* __restrict__ W3,
                              unsigned short* __restrict__ out) {
    __shared__ float tile[32][33];
    const float* src = blockIdx.z == 0 ? W0 : blockIdx.z == 1 ? W1 : blockIdx.z == 2 ? W2 : W3;
    unsigned short* dst = out + (size_t)blockIdx.z * 1024 * 1024;
    int lx = threadIdx.x & 31, ly8 = threadIdx.x >> 5;
    int x = blockIdx.x * 32 + lx;
#pragma unroll
    for (int i = 0; i < 4; i++) {
        int ly = ly8 + i * 8;
        tile[ly][lx] = src[(size_t)(blockIdx.y * 32 + ly) * 1024 + x];
    }
    __syncthreads();
    int tx = blockIdx.y * 32 + lx;
#pragma unroll
    for (int i = 0; i < 4; i++) {
        int ty = ly8 + i * 8;
        dst[(size_t)(blockIdx.x * 32 + ty) * 1024 + tx] = f2bf(tile[lx][ty]);
    }
}

// ---- transpose v-part of C3: [B*2048 rows][3072] cols 2048.. -> v_t [B][1024][2048] ----
__global__ void k_transpose_v(const unsigned short* __restrict__ C3, unsigned short* __restrict__ out) {
    __shared__ unsigned short tile[32][33];
    int bz = blockIdx.z;
    int lx = threadIdx.x & 31, ly8 = threadIdx.x >> 5;
    int x = blockIdx.x * 32 + lx;  // v col (0..1023)
#pragma unroll
    for (int i = 0; i < 4; i++) {
        int y = blockIdx.y * 32 + ly8 + i * 8;  // row in batch (0..2047)
        tile[ly8 + i * 8][lx] = C3[(size_t)(bz * 2048 + y) * 3072 + 2048 + x];
    }
    __syncthreads();
    int tx = blockIdx.y * 32 + lx;
#pragma unroll
    for (int i = 0; i < 4; i++) {
        int ty = blockIdx.x * 32 + ly8 + i * 8;
        out[(size_t)bz * 1024 * 2048 + (size_t)ty * 2048 + tx] = tile[lx][ly8 + i * 8];
    }
}

// ---------------- row dot: out[row] = (sigmoid?) <A[row,:], x> ----------------
__global__ void k_rowdot(const float* __restrict__ A, const float* __restrict__ x,
                         float* __restrict__ out, int ncols, int sig) {
    int lane = threadIdx.x & 63;
    int row = blockIdx.x * 4 + (threadIdx.x >> 6);
    const float4* a = reinterpret_cast<const float4*>(A + (size_t)row * ncols);
    const float4* xv = reinterpret_cast<const float4*>(x);
    float s = 0.f;
    int n4 = ncols >> 2;
    for (int i = lane; i < n4; i += 64) {
        float4 av = a[i], bv = xv[i];
        s += av.x * bv.x + av.y * bv.y + av.z * bv.z + av.w * bv.w;
    }
#pragma unroll
    for (int o = 1; o < 64; o <<= 1) s += __shfl_xor(s, o);
    if (lane == 0) out[row] = sig ? (1.f / (1.f + __expf(-s))) : s;
}

// ---------------- row softmax: f32 [8192][2048] -> bf16 probs ----------------
__global__ __launch_bounds__(256) void k_softmax(const float* __restrict__ logits,
                                                 unsigned short* __restrict__ probs) {
    __shared__ float red[8];
    size_t base = (size_t)blockIdx.x * 2048;
    const float4* src = reinterpret_cast<const float4*>(logits + base);
    int t = threadIdx.x;
    int wave = t >> 6, lane = t & 63;
    float4 v0 = src[t], v1 = src[t + 256];
    float m = fmaxf(fmaxf(fmaxf(v0.x, v0.y), fmaxf(v0.z, v0.w)),
                    fmaxf(fmaxf(v1.x, v1.y), fmaxf(v1.z, v1.w)));
#pragma unroll
    for (int o = 1; o < 64; o <<= 1) m = fmaxf(m, __shfl_xor(m, o));
    if (lane == 0) red[wave] = m;
    __syncthreads();
    m = fmaxf(fmaxf(red[0], red[1]), fmaxf(red[2], red[3]));
    float e[8];
    e[0] = __expf(v0.x - m); e[1] = __expf(v0.y - m);
    e[2] = __expf(v0.z - m); e[3] = __expf(v0.w - m);
    e[4] = __expf(v1.x - m); e[5] = __expf(v1.y - m);
    e[6] = __expf(v1.z - m); e[7] = __expf(v1.w - m);
    float s = e[0] + e[1] + e[2] + e[3] + e[4] + e[5] + e[6] + e[7];
#pragma unroll
    for (int o = 1; o < 64; o <<= 1) s += __shfl_xor(s, o);
    if (lane == 0) red[4 + wave] = s;
    __syncthreads();
    s = red[4] + red[5] + red[6] + red[7];
    float inv = 1.f / s;
    union { unsigned short u[4]; uint2 q; } o0, o1;
#pragma unroll
    for (int j = 0; j < 4; j++) o0.u[j] = f2bf(e[j] * inv);
#pragma unroll
    for (int j = 0; j < 4; j++) o1.u[j] = f2bf(e[4 + j] * inv);
    reinterpret_cast<uint2*>(probs + base)[t] = o0.q;
    reinterpret_cast<uint2*>(probs + base)[t + 256] = o1.q;
}

// ================= phased 256-row GEMM: C[M,N] = A[M,K] @ Bt[N,K]^T =================
// BM=256, BK=64, 512 threads (8 waves).
// BN=256: waves 2Mx4N (wave 128x64), 8 phases / 2 K-tiles, MP=2 -> 16 MFMA/phase.
// BN=128: waves 4Mx2N (wave 64x64),  4 phases / 2 K-tiles, MP=2 -> 16 MFMA/phase.
// B-frags are register-held after the first phase of each K-tile, so B LDS region
// is dead afterward; A staged 1 tile ahead, B 2 tiles ahead; counted vmcnt leaves
// exactly the next-next B pair in flight. XOR swizzle slot^=(row&7) both-sides.
template <int BN>
struct Geo {
    static constexpr int WN = BN / 64;        // waves along N
    static constexpr int WM = 8 / WN;         // waves along M
    static constexpr int WROWS = 256 / WM;    // per-wave M extent
    static constexpr int MF = WROWS / 16;     // M fragments per wave
    static constexpr int MP = 2;              // M fragments per phase
    static constexpr int ASZ = 256 * 64 * 2;  // 32 KB
    static constexpr int BSZ = BN * 64 * 2;
    static constexpr int BUFSZ = ASZ + BSZ;
};

#define GPH(BUFOFF, MB, LB, STG, VMW)                                                   \
    {                                                                                   \
        const char* aB = smem + (BUFOFF);                                               \
        const char* bB = aB + G::ASZ;                                                   \
        bf16x8 af[G::MP * 2];                                                           \
        _Pragma("unroll") for (int mm = 0; mm < G::MP; ++mm)                            \
        _Pragma("unroll") for (int kk = 0; kk < 2; ++kk) {                              \
            int rowx = wrow + ((MB) + mm) * 16 + fr;                                    \
            int slot = (kk * 4 + kq) ^ (rowx & 7);                                      \
            af[mm * 2 + kk] = *reinterpret_cast<const bf16x8*>(aB + rowx * 128 + slot * 16); \
        }                                                                               \
        if (LB) {                                                                       \
            _Pragma("unroll") for (int nn = 0; nn < 4; ++nn)                            \
            _Pragma("unroll") for (int kk = 0; kk < 2; ++kk) {                          \
                int rowx = wcol + nn * 16 + fr;                                         \
                int slot = (kk * 4 + kq) ^ (rowx & 7);                                  \
                bfrag[nn * 2 + kk] = *reinterpret_cast<const bf16x8*>(bB + rowx * 128 + slot * 16); \
            }                                                                           \
        }                                                                               \
        STG;                                                                            \
        __builtin_amdgcn_sched_barrier(0);                                              \
        VMW;                                                                            \
        __builtin_amdgcn_s_barrier();                                                   \
        asm volatile("s_waitcnt lgkmcnt(0)" ::: "memory");                              \
        __builtin_amdgcn_sched_barrier(0);                                              \
        __builtin_amdgcn_s_setprio(1);                                                  \
        _Pragma("unroll") for (int mm = 0; mm < G::MP; ++mm)                            \
        _Pragma("unroll") for (int nn = 0; nn < 4; ++nn)                                \
        _Pragma("unroll") for (int kk = 0; kk < 2; ++kk)                                \
            acc[(MB) + mm][nn] = __builtin_amdgcn_mfma_f32_16x16x32_bf16(               \
                af[mm * 2 + kk], bfrag[nn * 2 + kk], acc[(MB) + mm][nn], 0, 0, 0);      \
        __builtin_amdgcn_s_setprio(0);                                                  \
        __builtin_amdgcn_sched_barrier(0);                                              \
        __builtin_amdgcn_s_barrier();                                                   \
        __builtin_amdgcn_sched_barrier(0);                                              \
    }

template <int EPI, int BN>
__global__ __launch_bounds__(512, 2) void k_gemm8(
    const unsigned short* __restrict__ A, int ldA, long long bsA,
    const unsigned short* __restrict__ Bt, int ldB, long long bsB,
    void* __restrict__ Cv, int ldC, long long bsC,
    const unsigned short* __restrict__ Qm, int ldQ,
    const float* __restrict__ gates, float alpha, int K, int NX, int NY) {
    using G = Geo<BN>;
    extern __shared__ char smem[];
    const int NT = K >> 6, NI = K >> 7;

    // bijective XCD swizzle (grid is always a multiple of 8)
    unsigned b = blockIdx.x;
    unsigned wg = (b & 7) * (gridDim.x >> 3) + (b >> 3);
    int xT = wg % NX;
    unsigned r2 = wg / NX;
    int yT = r2 % NY;
    int zB = r2 / NY;

    const unsigned short* Ab = A + (size_t)zB * (size_t)bsA;
    const unsigned short* Bb = Bt + (size_t)zB * (size_t)bsB;

    int t = threadIdx.x, lane = t & 63, wave = t >> 6;
    int wc = wave % G::WN, wr = wave / G::WN;
    int fr = lane & 15, kq = lane >> 4;
    int wrow = wr * G::WROWS, wcol = wc * 64;
    int trow = t >> 3, csx = (t & 7) ^ (trow & 7);
    long long rowTile = (long long)yT * 256, colTile = (long long)xT * BN;

    f32x4 acc[G::MF][4];
#pragma unroll
    for (int m = 0; m < G::MF; ++m)
#pragma unroll
        for (int n = 0; n < 4; ++n) acc[m][n] = (f32x4){0.f, 0.f, 0.f, 0.f};
    bf16x8 bfrag[8];

    auto stageA = [&](int buf, int h, int tt) {
        int kt = tt < NT ? tt : NT - 1;
#pragma unroll
        for (int rr = 0; rr < 2; ++rr) {
            const unsigned short* src =
                Ab + (size_t)(rowTile + h * 128 + rr * 64 + trow) * (size_t)ldA + kt * 64 + csx * 8;
            gload16(src, smem + buf * G::BUFSZ + h * 16384 + rr * 8192 + t * 16);
        }
    };
    auto stageB = [&](int buf, int h, int tt) {
        int kt = tt < NT ? tt : NT - 1;
        if (BN == 256) {
#pragma unroll
            for (int rr = 0; rr < 2; ++rr) {
                const unsigned short* src =
                    Bb + (size_t)(colTile + h * 128 + rr * 64 + trow) * (size_t)ldB + kt * 64 + csx * 8;
                gload16(src, smem + buf * G::BUFSZ + G::ASZ + h * 16384 + rr * 8192 + t * 16);
            }
        } else {
            const unsigned short* src =
                Bb + (size_t)(colTile + h * 64 + trow) * (size_t)ldB + kt * 64 + csx * 8;
            gload16(src, smem + buf * G::BUFSZ + G::ASZ + h * 8192 + t * 16);
        }
    };

    if constexpr (BN == 256) {
        // prologue: tile0 full + tile1 B, drain all
        stageA(0, 0, 0); stageA(0, 1, 0);
        stageB(0, 0, 0); stageB(0, 1, 0);
        stageB(1, 0, 1); stageB(1, 1, 1);
        __builtin_amdgcn_sched_barrier(0);
        vm_wait<0>();
        __builtin_amdgcn_s_barrier();
        __builtin_amdgcn_sched_barrier(0);

        for (int i = 0; i < NI; ++i) {
            int t1 = 2 * i + 1, t2 = 2 * i + 2, t3 = 2 * i + 3;
            GPH(0,          0,         1, stageA(1, 0, t1), (void)0);
            GPH(0,          G::MP,     0, stageA(1, 1, t1), (void)0);
            GPH(0,          2 * G::MP, 0, stageB(0, 0, t2), (void)0);
            GPH(0,          3 * G::MP, 0, stageB(0, 1, t2), vm_wait<4>());
            GPH(G::BUFSZ,   0,         1, stageA(0, 0, t2), (void)0);
            GPH(G::BUFSZ,   G::MP,     0, stageA(0, 1, t2), (void)0);
            GPH(G::BUFSZ,   2 * G::MP, 0, stageB(1, 0, t3), (void)0);
            GPH(G::BUFSZ,   3 * G::MP, 0, stageB(1, 1, t3), vm_wait<4>());
        }
    } else {
        // prologue: tile0 full, tile1 B issued and left in flight (2 loads)
        stageA(0, 0, 0); stageA(0, 1, 0);
        stageB(0, 0, 0); stageB(0, 1, 0);
        stageB(1, 0, 1); stageB(1, 1, 1);
        __builtin_amdgcn_sched_barrier(0);
        vm_wait<2>();
        __builtin_amdgcn_s_barrier();
        __builtin_amdgcn_sched_barrier(0);

        // 4 phases / 2 K-tiles, 16 MFMA per phase.
        // steady state: entering ph1, outstanding = B(buf1, t1) x2
        for (int i = 0; i < NI; ++i) {
            int t1 = 2 * i + 1, t2 = 2 * i + 2, t3 = 2 * i + 3;
            GPH(0,        0, 1, stageA(1, 0, t1), (void)0);
            GPH(0,        2, 0, (stageA(1, 1, t1), stageB(0, 0, t2), stageB(0, 1, t2)), vm_wait<2>());
            GPH(G::BUFSZ, 0, 1, stageA(0, 0, t2), (void)0);
            GPH(G::BUFSZ, 2, 0, (stageA(0, 1, t2), stageB(1, 0, t3), stageB(1, 1, t3)), vm_wait<2>());
        }
    }
    vm_wait<0>();

    // epilogue
    long long rb0 = rowTile + wrow + kq * 4;
    long long cb0 = colTile + wcol + fr;
    if (EPI == 0) {
        unsigned short* C = (unsigned short*)Cv + (size_t)zB * (size_t)bsC;
#pragma unroll
        for (int m = 0; m < G::MF; ++m)
#pragma unroll
            for (int n = 0; n < 4; ++n)
#pragma unroll
                for (int r = 0; r < 4; ++r)
                    C[(size_t)(rb0 + m * 16 + r) * (size_t)ldC + cb0 + n * 16] =
                        f2bf(acc[m][n][r] * alpha);
    } else if (EPI == 1) {
        unsigned short* C = (unsigned short*)Cv;
#pragma unroll
        for (int m = 0; m < G::MF; ++m)
#pragma unroll
            for (int r = 0; r < 4; ++r) {
                long long row = rb0 + m * 16 + r;
                float g = gates[row];
#pragma unroll
                for (int n = 0; n < 4; ++n) {
                    long long col = cb0 + n * 16;
                    float v = (bf2f(Qm[(size_t)row * (size_t)ldQ + col]) + g * acc[m][n][r]) * alpha;
                    C[(size_t)row * (size_t)ldC + col] = f2bf(v);
                }
            }
    } else {
        float* C = (float*)Cv + (size_t)zB * (size_t)bsC;
#pragma unroll
        for (int m = 0; m < G::MF; ++m)
#pragma unroll
            for (int n = 0; n < 4; ++n)
#pragma unroll
                for (int r = 0; r < 4; ++r)
                    C[(size_t)(rb0 + m * 16 + r) * (size_t)ldC + cb0 + n * 16] =
                        acc[m][n][r] * alpha;
    }
}

extern "C" void kernel_launch(void* const* d_in, const int* in_sizes, int n_in,
                              void* d_out, int out_size, void* d_ws, size_t ws_size,
                              hipStream_t stream) {
    const float* hs = (const float*)d_in[0];
    const float* pa = (const float*)d_in[1];
    const float* Wq = (const float*)d_in[2];
    const float* Wk = (const float*)d_in[3];
    const float* Wv = (const float*)d_in[4];
    const float* Wm = (const float*)d_in[5];
    const float* wg = (const float*)d_in[6];
    float* out = (float*)d_out;

    const int B = 4, S = 2048, H = 1024;
    const size_t BS = (size_t)B * S;       // 8192
    const size_t BSH = BS * H;             // 8.39M
    const size_t BSS = (size_t)B * S * S;  // 16.8M
    const float inv_sqrt_h = 0.03125f;
    const float decay = 0.60653065971263342f;  // exp(-0.5)

    char* ws = (char*)d_ws;
    size_t off = 0;
    auto take = [&](size_t bytes) {
        char* p = ws + off;
        off += (bytes + 255) & ~(size_t)255;
        return p;
    };
    unsigned short* hs_bf = (unsigned short*)take(BSH * 2);        // reused as u_bf
    unsigned short* WT    = (unsigned short*)take(4ull * H * H * 2);  // [Wq^T;Wk^T;Wv^T;Wm^T]
    float* wg2            = (float*)take(H * 4);
    float* gates          = (float*)take(BS * 4);
    unsigned short* C3    = (unsigned short*)take(BS * 3 * H * 2); // q|k|v merged [8192][3072]
    unsigned short* v_t   = (unsigned short*)take(BSH * 2);        // [B][1024][2048]
    unsigned short* pa_bf = (unsigned short*)take(BSS * 2);        // reused as probs
    float* logits         = (float*)take(BSS * 4);
    unsigned short* mv    = (unsigned short*)d_out;  // scratch: dead before final write
    unsigned short* u_bf  = hs_bf;
    unsigned short* probs = pa_bf;
    unsigned short* WmT   = WT + 3ull * H * H;

    // allow >64KB dynamic LDS (ignore errors)
    (void)hipFuncSetAttribute((const void*)k_gemm8<0, 128>, hipFuncAttributeMaxDynamicSharedMemorySize, 98304);
    (void)hipFuncSetAttribute((const void*)k_gemm8<1, 128>, hipFuncAttributeMaxDynamicSharedMemorySize, 98304);
    (void)hipFuncSetAttribute((const void*)k_gemm8<2, 128>, hipFuncAttributeMaxDynamicSharedMemorySize, 98304);
    (void)hipFuncSetAttribute((const void*)k_gemm8<2, 256>, hipFuncAttributeMaxDynamicSharedMemorySize, 131072);

    // conversions
    k_convert_scale<<<dim3((unsigned)(BSH / 4 / 256)), 256, 0, stream>>>(hs, hs_bf, (int)(BSH / 4), 1.0f);
    k_convert_scale<<<dim3((unsigned)(BSS / 4 / 256)), 256, 0, stream>>>(pa, pa_bf, (int)(BSS / 4), decay);
    k_transpose_w<<<dim3(32, 32, 4), 256, 0, stream>>>(Wq, Wk, Wv, Wm, WT);
    k_rowdot<<<dim3(H / 4), 256, 0, stream>>>(Wq, wg, wg2, H, 0);
    k_rowdot<<<dim3((unsigned)(BS / 4)), 256, 0, stream>>>(hs, wg2, gates, H, 1);

    // QKV merged: C3[8192][3072] = hs_bf @ [Wq|Wk|Wv]   (grid 24x32 = 768)
    k_gemm8<0, 128><<<768, 512, 98304, stream>>>(
        hs_bf, H, 0, WT, H, 0, C3, 3 * H, 0, nullptr, 0, nullptr, 1.f, H, 24, 32);
    // v^T per batch from C3 v-columns
    k_transpose_v<<<dim3(32, 64, 4), 256, 0, stream>>>(C3, v_t);
    // mv = (pa*decay) @ v   [batched]  (grid 8x8x4 = 256)
    k_gemm8<0, 128><<<256, 512, 98304, stream>>>(
        pa_bf, S, (long long)S * S, v_t, S, (long long)H * S, mv, H, (long long)S * H,
        nullptr, 0, nullptr, 1.f, S, 8, 8);
    // u = (q + gates * (mv @ Wm)) * inv_sqrt_h   (grid 8x32 = 256)
    k_gemm8<1, 128><<<256, 512, 98304, stream>>>(
        mv, H, 0, WmT, H, 0, u_bf, H, 0, C3, 3 * H, gates, inv_sqrt_h, H, 8, 32);
    // logits = u @ k^T   [batched]  (grid 8x8x4 = 256, 256x256 tiles)
    k_gemm8<2, 256><<<256, 512, 131072, stream>>>(
        u_bf, H, (long long)S * H, C3 + H, 3 * H, (long long)S * 3 * H,
        logits, S, (long long)S * S, nullptr, 0, nullptr, 1.f, H, 8, 8);
    // softmax rows
    k_softmax<<<dim3((unsigned)BS), 256, 0, stream>>>(logits, probs);
    // context = probs @ v   [batched] -> d_out f32  (grid 8x8x4 = 256)
    k_gemm8<2, 128><<<256, 512, 98304, stream>>>(
        probs, S, (long long)S * S, v_t, S, (long long)H * S, out, H, (long long)S * H,
        nullptr, 0, nullptr, 1.f, S, 8, 8);
}

// Round 4
// 304.772 us; speedup vs baseline: 1.0138x; 1.0138x over previous
//
#include <hip/hip_runtime.h>
#include <hip/hip_bf16.h>

typedef __attribute__((ext_vector_type(4))) float f32x4;
typedef __attribute__((ext_vector_type(8))) __bf16 bf16x8;

__device__ __forceinline__ unsigned short f2bf(float f) {
    union { float f; unsigned u; } x; x.f = f;
    unsigned r = x.u + 0x7fffu + ((x.u >> 16) & 1u);
    return (unsigned short)(r >> 16);
}
__device__ __forceinline__ float bf2f(unsigned short b) {
    union { unsigned u; float f; } x; x.u = ((unsigned)b) << 16;
    return x.f;
}

__device__ __forceinline__ void gload16(const void* g, void* l) {
    __builtin_amdgcn_global_load_lds(
        (const __attribute__((address_space(1))) unsigned int*)g,
        (__attribute__((address_space(3))) unsigned int*)l,
        16, 0, 0);
}

template <int N> __device__ __forceinline__ void vm_wait();
template <> __device__ __forceinline__ void vm_wait<0>() { asm volatile("s_waitcnt vmcnt(0)" ::: "memory"); }
template <> __device__ __forceinline__ void vm_wait<2>() { asm volatile("s_waitcnt vmcnt(2)" ::: "memory"); }
template <> __device__ __forceinline__ void vm_wait<4>() { asm volatile("s_waitcnt vmcnt(4)" ::: "memory"); }

// ---------------- elementwise convert (f32 -> bf16, with scale) ----------------
__global__ void k_convert_scale(const float* __restrict__ in, unsigned short* __restrict__ out,
                                int n4, float scale) {
    int i = blockIdx.x * 256 + threadIdx.x;
    if (i >= n4) return;
    float4 v = reinterpret_cast<const float4*>(in)[i];
    union { unsigned short u[4]; uint2 q; } o;
    o.u[0] = f2bf(v.x * scale);
    o.u[1] = f2bf(v.y * scale);
    o.u[2] = f2bf(v.z * scale);
    o.u[3] = f2bf(v.w * scale);
    reinterpret_cast<uint2*>(out)[i] = o.q;
}

// ---------------- reduce two f32 partials ----------------
__global__ void k_reduce2_bf(const float* __restrict__ p0, const float* __restrict__ p1,
                             unsigned short* __restrict__ out, int n4) {
    int i = blockIdx.x * 256 + threadIdx.x;
    if (i >= n4) return;
    float4 a = reinterpret_cast<const float4*>(p0)[i];
    float4 b = reinterpret_cast<const float4*>(p1)[i];
    union { unsigned short u[4]; uint2 q; } o;
    o.u[0] = f2bf(a.x + b.x);
    o.u[1] = f2bf(a.y + b.y);
    o.u[2] = f2bf(a.z + b.z);
    o.u[3] = f2bf(a.w + b.w);
    reinterpret_cast<uint2*>(out)[i] = o.q;
}
__global__ void k_reduce2_f32(const float* __restrict__ p0, const float* __restrict__ p1,
                              float* __restrict__ out, int n4) {
    int i = blockIdx.x * 256 + threadIdx.x;
    if (i >= n4) return;
    float4 a = reinterpret_cast<const float4*>(p0)[i];
    float4 b = reinterpret_cast<const float4*>(p1)[i];
    float4 o;
    o.x = a.x + b.x; o.y = a.y + b.y; o.z = a.z + b.z; o.w = a.w + b.w;
    reinterpret_cast<float4*>(out)[i] = o;
}

// ---------------- transpose 4x [1024x1024] f32 -> bf16 (W^T) ----------------
__global__ void k_transpose_w(const float* __restrict__ W0, const float* __restrict__ W1,
                              const float* __restrict__ W2, const float* __restrict__ W3,
                              unsigned short* __restrict__ out) {
    __shared__ float tile[32][33];
    const float* src = blockIdx.z == 0 ? W0 : blockIdx.z == 1 ? W1 : blockIdx.z == 2 ? W2 : W3;
    unsigned short* dst = out + (size_t)blockIdx.z * 1024 * 1024;
    int lx = threadIdx.x & 31, ly8 = threadIdx.x >> 5;
    int x = blockIdx.x * 32 + lx;
#pragma unroll
    for (int i = 0; i < 4; i++) {
        int ly = ly8 + i * 8;
        tile[ly][lx] = src[(size_t)(blockIdx.y * 32 + ly) * 1024 + x];
    }
    __syncthreads();
    int tx = blockIdx.y * 32 + lx;
#pragma unroll
    for (int i = 0; i < 4; i++) {
        int ty = ly8 + i * 8;
        dst[(size_t)(blockIdx.x * 32 + ty) * 1024 + tx] = f2bf(tile[lx][ty]);
    }
}

// ---- transpose v-part of C3: [B*2048 rows][3072] cols 2048.. -> v_t [B][1024][2048] ----
__global__ void k_transpose_v(const unsigned short* __restrict__ C3, unsigned short* __restrict__ out) {
    __shared__ unsigned short tile[32][33];
    int bz = blockIdx.z;
    int lx = threadIdx.x & 31, ly8 = threadIdx.x >> 5;
    int x = blockIdx.x * 32 + lx;  // v col (0..1023)
#pragma unroll
    for (int i = 0; i < 4; i++) {
        int y = blockIdx.y * 32 + ly8 + i * 8;  // row in batch (0..2047)
        tile[ly8 + i * 8][lx] = C3[(size_t)(bz * 2048 + y) * 3072 + 2048 + x];
    }
    __syncthreads();
    int tx = blockIdx.y * 32 + lx;
#pragma unroll
    for (int i = 0; i < 4; i++) {
        int ty = blockIdx.x * 32 + ly8 + i * 8;
        out[(size_t)bz * 1024 * 2048 + (size_t)ty * 2048 + tx] = tile[lx][ly8 + i * 8];
    }
}

// ---------------- row dot: out[row] = (sigmoid?) <A[row,:], x> ----------------
__global__ void k_rowdot(const float* __restrict__ A, const float* __restrict__ x,
                         float* __restrict__ out, int ncols, int sig) {
    int lane = threadIdx.x & 63;
    int row = blockIdx.x * 4 + (threadIdx.x >> 6);
    const float4* a = reinterpret_cast<const float4*>(A + (size_t)row * ncols);
    const float4* xv = reinterpret_cast<const float4*>(x);
    float s = 0.f;
    int n4 = ncols >> 2;
    for (int i = lane; i < n4; i += 64) {
        float4 av = a[i], bv = xv[i];
        s += av.x * bv.x + av.y * bv.y + av.z * bv.z + av.w * bv.w;
    }
#pragma unroll
    for (int o = 1; o < 64; o <<= 1) s += __shfl_xor(s, o);
    if (lane == 0) out[row] = sig ? (1.f / (1.f + __expf(-s))) : s;
}

// ---------------- row softmax: f32 [8192][2048] -> bf16 probs ----------------
__global__ __launch_bounds__(256) void k_softmax(const float* __restrict__ logits,
                                                 unsigned short* __restrict__ probs) {
    __shared__ float red[8];
    size_t base = (size_t)blockIdx.x * 2048;
    const float4* src = reinterpret_cast<const float4*>(logits + base);
    int t = threadIdx.x;
    int wave = t >> 6, lane = t & 63;
    float4 v0 = src[t], v1 = src[t + 256];
    float m = fmaxf(fmaxf(fmaxf(v0.x, v0.y), fmaxf(v0.z, v0.w)),
                    fmaxf(fmaxf(v1.x, v1.y), fmaxf(v1.z, v1.w)));
#pragma unroll
    for (int o = 1; o < 64; o <<= 1) m = fmaxf(m, __shfl_xor(m, o));
    if (lane == 0) red[wave] = m;
    __syncthreads();
    m = fmaxf(fmaxf(red[0], red[1]), fmaxf(red[2], red[3]));
    float e[8];
    e[0] = __expf(v0.x - m); e[1] = __expf(v0.y - m);
    e[2] = __expf(v0.z - m); e[3] = __expf(v0.w - m);
    e[4] = __expf(v1.x - m); e[5] = __expf(v1.y - m);
    e[6] = __expf(v1.z - m); e[7] = __expf(v1.w - m);
    float s = e[0] + e[1] + e[2] + e[3] + e[4] + e[5] + e[6] + e[7];
#pragma unroll
    for (int o = 1; o < 64; o <<= 1) s += __shfl_xor(s, o);
    if (lane == 0) red[4 + wave] = s;
    __syncthreads();
    s = red[4] + red[5] + red[6] + red[7];
    float inv = 1.f / s;
    union { unsigned short u[4]; uint2 q; } o0, o1;
#pragma unroll
    for (int j = 0; j < 4; j++) o0.u[j] = f2bf(e[j] * inv);
#pragma unroll
    for (int j = 0; j < 4; j++) o1.u[j] = f2bf(e[4 + j] * inv);
    reinterpret_cast<uint2*>(probs + base)[t] = o0.q;
    reinterpret_cast<uint2*>(probs + base)[t + 256] = o1.q;
}

// ================= 8-phase 256-row GEMM: C[M,N] = A[M,K] @ Bt[N,K]^T =================
// BM=256, BK=64, 512 threads (8 waves). BN=256: waves 2Mx4N (wave 128x64), MP=2 ->
// 16 MFMA/phase. BN=128: waves 4Mx2N (wave 64x64), MP=1 -> 8 MFMA/phase (round-2
// proven schedule). B-frags read once per K-tile (first phase), A staged 1 tile
// ahead, B 2 tiles ahead, counted vmcnt at ph4/ph8 only. XOR swizzle both-sides.
// Split-K: NC chunks decoded from blockIdx; A/B advanced c*K columns; C indexed by
// zC = c*NB + zB (partials laid out [chunk][batch][M][N]).
template <int BN>
struct Geo {
    static constexpr int WN = BN / 64;        // waves along N
    static constexpr int WM = 8 / WN;         // waves along M
    static constexpr int WROWS = 256 / WM;    // per-wave M extent
    static constexpr int MF = WROWS / 16;     // M fragments per wave
    static constexpr int MP = MF / 4;         // M fragments per phase
    static constexpr int ASZ = 256 * 64 * 2;  // 32 KB
    static constexpr int BSZ = BN * 64 * 2;
    static constexpr int BUFSZ = ASZ + BSZ;
};

#define GPH(BUFOFF, MB, LB, STG, VMW)                                                   \
    {                                                                                   \
        const char* aB = smem + (BUFOFF);                                               \
        const char* bB = aB + G::ASZ;                                                   \
        bf16x8 af[G::MP * 2];                                                           \
        _Pragma("unroll") for (int mm = 0; mm < G::MP; ++mm)                            \
        _Pragma("unroll") for (int kk = 0; kk < 2; ++kk) {                              \
            int rowx = wrow + ((MB) + mm) * 16 + fr;                                    \
            int slot = (kk * 4 + kq) ^ (rowx & 7);                                      \
            af[mm * 2 + kk] = *reinterpret_cast<const bf16x8*>(aB + rowx * 128 + slot * 16); \
        }                                                                               \
        if (LB) {                                                                       \
            _Pragma("unroll") for (int nn = 0; nn < 4; ++nn)                            \
            _Pragma("unroll") for (int kk = 0; kk < 2; ++kk) {                          \
                int rowx = wcol + nn * 16 + fr;                                         \
                int slot = (kk * 4 + kq) ^ (rowx & 7);                                  \
                bfrag[nn * 2 + kk] = *reinterpret_cast<const bf16x8*>(bB + rowx * 128 + slot * 16); \
            }                                                                           \
        }                                                                               \
        STG;                                                                            \
        __builtin_amdgcn_sched_barrier(0);                                              \
        VMW;                                                                            \
        __builtin_amdgcn_s_barrier();                                                   \
        asm volatile("s_waitcnt lgkmcnt(0)" ::: "memory");                              \
        __builtin_amdgcn_sched_barrier(0);                                              \
        __builtin_amdgcn_s_setprio(1);                                                  \
        _Pragma("unroll") for (int mm = 0; mm < G::MP; ++mm)                            \
        _Pragma("unroll") for (int nn = 0; nn < 4; ++nn)                                \
        _Pragma("unroll") for (int kk = 0; kk < 2; ++kk)                                \
            acc[(MB) + mm][nn] = __builtin_amdgcn_mfma_f32_16x16x32_bf16(               \
                af[mm * 2 + kk], bfrag[nn * 2 + kk], acc[(MB) + mm][nn], 0, 0, 0);      \
        __builtin_amdgcn_s_setprio(0);                                                  \
        __builtin_amdgcn_sched_barrier(0);                                              \
        __builtin_amdgcn_s_barrier();                                                   \
        __builtin_amdgcn_sched_barrier(0);                                              \
    }

template <int EPI, int BN>
__global__ __launch_bounds__(512, 2) void k_gemm8(
    const unsigned short* __restrict__ A, int ldA, long long bsA,
    const unsigned short* __restrict__ Bt, int ldB, long long bsB,
    void* __restrict__ Cv, int ldC, long long bsC,
    const unsigned short* __restrict__ Qm, int ldQ,
    const float* __restrict__ gates, float alpha, int K,
    int NX, int NY, int NB, int NC) {
    using G = Geo<BN>;
    extern __shared__ char smem[];
    const int NT = K >> 6, NI = K >> 7;

    // bijective XCD swizzle (grid is always a multiple of 8)
    unsigned b = blockIdx.x;
    unsigned wg = (b & 7) * (gridDim.x >> 3) + (b >> 3);
    int xT = wg % NX;
    unsigned r2 = wg / NX;
    int yT = r2 % NY;
    unsigned r3 = r2 / NY;
    int zB = r3 % NB;
    int c = r3 / NB;
    int zC = c * NB + zB;

    const unsigned short* Ab = A + (size_t)zB * (size_t)bsA + (size_t)c * (size_t)K;
    const unsigned short* Bb = Bt + (size_t)zB * (size_t)bsB + (size_t)c * (size_t)K;

    int t = threadIdx.x, lane = t & 63, wave = t >> 6;
    int wc = wave % G::WN, wr = wave / G::WN;
    int fr = lane & 15, kq = lane >> 4;
    int wrow = wr * G::WROWS, wcol = wc * 64;
    int trow = t >> 3, csx = (t & 7) ^ (trow & 7);
    long long rowTile = (long long)yT * 256, colTile = (long long)xT * BN;

    f32x4 acc[G::MF][4];
#pragma unroll
    for (int m = 0; m < G::MF; ++m)
#pragma unroll
        for (int n = 0; n < 4; ++n) acc[m][n] = (f32x4){0.f, 0.f, 0.f, 0.f};
    bf16x8 bfrag[8];

    auto stageA = [&](int buf, int h, int tt) {
        int kt = tt < NT ? tt : NT - 1;
#pragma unroll
        for (int rr = 0; rr < 2; ++rr) {
            const unsigned short* src =
                Ab + (size_t)(rowTile + h * 128 + rr * 64 + trow) * (size_t)ldA + kt * 64 + csx * 8;
            gload16(src, smem + buf * G::BUFSZ + h * 16384 + rr * 8192 + t * 16);
        }
    };
    auto stageB = [&](int buf, int h, int tt) {
        int kt = tt < NT ? tt : NT - 1;
        if (BN == 256) {
#pragma unroll
            for (int rr = 0; rr < 2; ++rr) {
                const unsigned short* src =
                    Bb + (size_t)(colTile + h * 128 + rr * 64 + trow) * (size_t)ldB + kt * 64 + csx * 8;
                gload16(src, smem + buf * G::BUFSZ + G::ASZ + h * 16384 + rr * 8192 + t * 16);
            }
        } else {
            const unsigned short* src =
                Bb + (size_t)(colTile + h * 64 + trow) * (size_t)ldB + kt * 64 + csx * 8;
            gload16(src, smem + buf * G::BUFSZ + G::ASZ + h * 8192 + t * 16);
        }
    };

    // prologue: tile0 full + tile1 B, drain all
    stageA(0, 0, 0); stageA(0, 1, 0);
    stageB(0, 0, 0); stageB(0, 1, 0);
    stageB(1, 0, 1); stageB(1, 1, 1);
    __builtin_amdgcn_sched_barrier(0);
    vm_wait<0>();
    __builtin_amdgcn_s_barrier();
    __builtin_amdgcn_sched_barrier(0);

    constexpr int VMN = (BN == 256) ? 4 : 2;
    for (int i = 0; i < NI; ++i) {
        int t1 = 2 * i + 1, t2 = 2 * i + 2, t3 = 2 * i + 3;
        GPH(0,          0,         1, stageA(1, 0, t1), (void)0);
        GPH(0,          G::MP,     0, stageA(1, 1, t1), (void)0);
        GPH(0,          2 * G::MP, 0, stageB(0, 0, t2), (void)0);
        GPH(0,          3 * G::MP, 0, stageB(0, 1, t2), vm_wait<VMN>());
        GPH(G::BUFSZ,   0,         1, stageA(0, 0, t2), (void)0);
        GPH(G::BUFSZ,   G::MP,     0, stageA(0, 1, t2), (void)0);
        GPH(G::BUFSZ,   2 * G::MP, 0, stageB(1, 0, t3), (void)0);
        GPH(G::BUFSZ,   3 * G::MP, 0, stageB(1, 1, t3), vm_wait<VMN>());
    }
    vm_wait<0>();

    // epilogue
    long long rb0 = rowTile + wrow + kq * 4;
    long long cb0 = colTile + wcol + fr;
    if (EPI == 0) {
        unsigned short* C = (unsigned short*)Cv + (size_t)zC * (size_t)bsC;
#pragma unroll
        for (int m = 0; m < G::MF; ++m)
#pragma unroll
            for (int n = 0; n < 4; ++n)
#pragma unroll
                for (int r = 0; r < 4; ++r)
                    C[(size_t)(rb0 + m * 16 + r) * (size_t)ldC + cb0 + n * 16] =
                        f2bf(acc[m][n][r] * alpha);
    } else if (EPI == 1) {
        unsigned short* C = (unsigned short*)Cv;
#pragma unroll
        for (int m = 0; m < G::MF; ++m)
#pragma unroll
            for (int r = 0; r < 4; ++r) {
                long long row = rb0 + m * 16 + r;
                float g = gates[row];
#pragma unroll
                for (int n = 0; n < 4; ++n) {
                    long long col = cb0 + n * 16;
                    float v = (bf2f(Qm[(size_t)row * (size_t)ldQ + col]) + g * acc[m][n][r]) * alpha;
                    C[(size_t)row * (size_t)ldC + col] = f2bf(v);
                }
            }
    } else {
        float* C = (float*)Cv + (size_t)zC * (size_t)bsC;
#pragma unroll
        for (int m = 0; m < G::MF; ++m)
#pragma unroll
            for (int n = 0; n < 4; ++n)
#pragma unroll
                for (int r = 0; r < 4; ++r)
                    C[(size_t)(rb0 + m * 16 + r) * (size_t)ldC + cb0 + n * 16] =
                        acc[m][n][r] * alpha;
    }
}

extern "C" void kernel_launch(void* const* d_in, const int* in_sizes, int n_in,
                              void* d_out, int out_size, void* d_ws, size_t ws_size,
                              hipStream_t stream) {
    const float* hs = (const float*)d_in[0];
    const float* pa = (const float*)d_in[1];
    const float* Wq = (const float*)d_in[2];
    const float* Wk = (const float*)d_in[3];
    const float* Wv = (const float*)d_in[4];
    const float* Wm = (const float*)d_in[5];
    const float* wg = (const float*)d_in[6];
    float* out = (float*)d_out;

    const int B = 4, S = 2048, H = 1024;
    const size_t BS = (size_t)B * S;       // 8192
    const size_t BSH = BS * H;             // 8.39M
    const size_t BSS = (size_t)B * S * S;  // 16.8M
    const float inv_sqrt_h = 0.03125f;
    const float decay = 0.60653065971263342f;  // exp(-0.5)

    char* ws = (char*)d_ws;
    size_t off = 0;
    auto take = [&](size_t bytes) {
        char* p = ws + off;
        off += (bytes + 255) & ~(size_t)255;
        return p;
    };
    unsigned short* hs_bf = (unsigned short*)take(BSH * 2);        // reused as u_bf
    unsigned short* WT    = (unsigned short*)take(4ull * H * H * 2);  // [Wq^T;Wk^T;Wv^T;Wm^T]
    float* wg2            = (float*)take(H * 4);
    float* gates          = (float*)take(BS * 4);
    unsigned short* C3    = (unsigned short*)take(BS * 3 * H * 2); // q|k|v merged [8192][3072]
    unsigned short* v_t   = (unsigned short*)take(BSH * 2);        // [B][1024][2048]
    unsigned short* pa_bf = (unsigned short*)take(BSS * 2);        // reused as probs
    float* logits         = (float*)take(BSS * 4);                 // reused as split-K partials
    unsigned short* mv    = (unsigned short*)d_out;  // scratch: dead before final write
    unsigned short* u_bf  = hs_bf;
    unsigned short* probs = pa_bf;
    unsigned short* WmT   = WT + 3ull * H * H;
    float* part0 = logits;                  // [chunk0][b][2048][1024] f32
    float* part1 = logits + BSH;            // [chunk1][b][2048][1024] f32

    // allow >64KB dynamic LDS (ignore errors)
    (void)hipFuncSetAttribute((const void*)k_gemm8<0, 256>, hipFuncAttributeMaxDynamicSharedMemorySize, 131072);
    (void)hipFuncSetAttribute((const void*)k_gemm8<1, 128>, hipFuncAttributeMaxDynamicSharedMemorySize, 98304);
    (void)hipFuncSetAttribute((const void*)k_gemm8<2, 256>, hipFuncAttributeMaxDynamicSharedMemorySize, 131072);

    // conversions
    k_convert_scale<<<dim3((unsigned)(BSH / 4 / 256)), 256, 0, stream>>>(hs, hs_bf, (int)(BSH / 4), 1.0f);
    k_convert_scale<<<dim3((unsigned)(BSS / 4 / 256)), 256, 0, stream>>>(pa, pa_bf, (int)(BSS / 4), decay);
    k_transpose_w<<<dim3(32, 32, 4), 256, 0, stream>>>(Wq, Wk, Wv, Wm, WT);
    k_rowdot<<<dim3(H / 4), 256, 0, stream>>>(Wq, wg, wg2, H, 0);
    k_rowdot<<<dim3((unsigned)(BS / 4)), 256, 0, stream>>>(hs, wg2, gates, H, 1);

    // QKV merged: C3[8192][3072] = hs_bf @ [Wq|Wk|Wv]   (256x256 tiles, grid 12x32 = 384)
    k_gemm8<0, 256><<<384, 512, 131072, stream>>>(
        hs_bf, H, 0, WT, H, 0, C3, 3 * H, 0, nullptr, 0, nullptr, 1.f, H, 12, 32, 1, 1);
    // v^T per batch from C3 v-columns
    k_transpose_v<<<dim3(32, 64, 4), 256, 0, stream>>>(C3, v_t);
    // mv = (pa*decay) @ v   [batched, split-K2]  (grid 4x8x4x2 = 256) -> f32 partials
    k_gemm8<2, 256><<<256, 512, 131072, stream>>>(
        pa_bf, S, (long long)S * S, v_t, S, (long long)H * S, part0, H, (long long)S * H,
        nullptr, 0, nullptr, 1.f, S / 2, 4, 8, 4, 2);
    k_reduce2_bf<<<dim3((unsigned)(BSH / 4 / 256)), 256, 0, stream>>>(part0, part1, mv, (int)(BSH / 4));
    // u = (q + gates * (mv @ Wm)) * inv_sqrt_h   (BN=128, grid 8x32 = 256)
    k_gemm8<1, 128><<<256, 512, 98304, stream>>>(
        mv, H, 0, WmT, H, 0, u_bf, H, 0, C3, 3 * H, gates, inv_sqrt_h, H, 8, 32, 1, 1);
    // logits = u @ k^T   [batched]  (grid 8x8x4 = 256, 256x256 tiles)
    k_gemm8<2, 256><<<256, 512, 131072, stream>>>(
        u_bf, H, (long long)S * H, C3 + H, 3 * H, (long long)S * 3 * H,
        logits, S, (long long)S * S, nullptr, 0, nullptr, 1.f, H, 8, 8, 4, 1);
    // softmax rows
    k_softmax<<<dim3((unsigned)BS), 256, 0, stream>>>(logits, probs);
    // context = probs @ v   [batched, split-K2]  (grid 4x8x4x2 = 256) -> f32 partials
    // (logits buffer is dead after softmax; reuse it for partials)
    k_gemm8<2, 256><<<256, 512, 131072, stream>>>(
        probs, S, (long long)S * S, v_t, S, (long long)H * S, part0, H, (long long)S * H,
        nullptr, 0, nullptr, 1.f, S / 2, 4, 8, 4, 2);
    k_reduce2_f32<<<dim3((unsigned)(BSH / 4 / 256)), 256, 0, stream>>>(part0, part1, out, (int)(BSH / 4));
}

// Round 5
// 267.296 us; speedup vs baseline: 1.1559x; 1.1402x over previous
//
#include <hip/hip_runtime.h>
#include <hip/hip_bf16.h>

typedef __attribute__((ext_vector_type(4))) float f32x4;
typedef __attribute__((ext_vector_type(8))) __bf16 bf16x8;

__device__ __forceinline__ unsigned short f2bf(float f) {
    union { float f; unsigned u; } x; x.f = f;
    unsigned r = x.u + 0x7fffu + ((x.u >> 16) & 1u);
    return (unsigned short)(r >> 16);
}
__device__ __forceinline__ float bf2f(unsigned short b) {
    union { unsigned u; float f; } x; x.u = ((unsigned)b) << 16;
    return x.f;
}

__device__ __forceinline__ void gload16(const void* g, void* l) {
    __builtin_amdgcn_global_load_lds(
        (const __attribute__((address_space(1))) unsigned int*)g,
        (__attribute__((address_space(3))) unsigned int*)l,
        16, 0, 0);
}

template <int N> __device__ __forceinline__ void vm_wait();
template <> __device__ __forceinline__ void vm_wait<0>() { asm volatile("s_waitcnt vmcnt(0)" ::: "memory"); }
template <> __device__ __forceinline__ void vm_wait<2>() { asm volatile("s_waitcnt vmcnt(2)" ::: "memory"); }
template <> __device__ __forceinline__ void vm_wait<4>() { asm volatile("s_waitcnt vmcnt(4)" ::: "memory"); }

// ======== prep: conv(pa*decay), conv(hs), transpose_w — fused by block range ========
__global__ __launch_bounds__(256) void k_prep(
    const float* __restrict__ hs, const float* __restrict__ pa,
    const float* __restrict__ Wq, const float* __restrict__ Wk,
    const float* __restrict__ Wv, const float* __restrict__ Wm,
    unsigned short* __restrict__ hs_bf, unsigned short* __restrict__ pa_bf,
    unsigned short* __restrict__ WT, float decay) {
    __shared__ float tile[32][33];
    unsigned b = blockIdx.x;
    int t = threadIdx.x;
    if (b < 16384u) {  // pa -> bf16 * decay (n4 = 4194304)
        int i = b * 256 + t;
        float4 v = reinterpret_cast<const float4*>(pa)[i];
        union { unsigned short u[4]; uint2 q; } o;
        o.u[0] = f2bf(v.x * decay); o.u[1] = f2bf(v.y * decay);
        o.u[2] = f2bf(v.z * decay); o.u[3] = f2bf(v.w * decay);
        reinterpret_cast<uint2*>(pa_bf)[i] = o.q;
    } else if (b < 24576u) {  // hs -> bf16 (n4 = 2097152)
        int i = (b - 16384u) * 256 + t;
        float4 v = reinterpret_cast<const float4*>(hs)[i];
        union { unsigned short u[4]; uint2 q; } o;
        o.u[0] = f2bf(v.x); o.u[1] = f2bf(v.y);
        o.u[2] = f2bf(v.z); o.u[3] = f2bf(v.w);
        reinterpret_cast<uint2*>(hs_bf)[i] = o.q;
    } else {  // transpose 4x [1024x1024] f32 -> bf16
        unsigned bb = b - 24576u;
        int z = bb >> 10, rem = bb & 1023;
        int bx = rem & 31, by = rem >> 5;
        const float* src = z == 0 ? Wq : z == 1 ? Wk : z == 2 ? Wv : Wm;
        unsigned short* dst = WT + (size_t)z * 1024 * 1024;
        int lx = t & 31, ly8 = t >> 5;
        int x = bx * 32 + lx;
#pragma unroll
        for (int i = 0; i < 4; i++)
            tile[ly8 + i * 8][lx] = src[(size_t)(by * 32 + ly8 + i * 8) * 1024 + x];
        __syncthreads();
        int tx = by * 32 + lx;
#pragma unroll
        for (int i = 0; i < 4; i++)
            dst[(size_t)(bx * 32 + ly8 + i * 8) * 1024 + tx] = f2bf(tile[lx][ly8 + i * 8]);
    }
}

// ======== post-QKV: transpose_v + gates = sigmoid(q . w_gate) — fused ========
__global__ __launch_bounds__(256) void k_post(
    const unsigned short* __restrict__ C3, unsigned short* __restrict__ v_t,
    const float* __restrict__ wg, float* __restrict__ gates) {
    __shared__ unsigned short tile[32][33];
    unsigned b = blockIdx.x;
    int t = threadIdx.x;
    if (b < 8192u) {  // transpose v-part of C3 -> v_t [B][1024][2048]
        int bx = b & 31, by = (b >> 5) & 63, bz = b >> 11;
        int lx = t & 31, ly8 = t >> 5;
        int x = bx * 32 + lx;
#pragma unroll
        for (int i = 0; i < 4; i++) {
            int y = by * 32 + ly8 + i * 8;
            tile[ly8 + i * 8][lx] = C3[(size_t)(bz * 2048 + y) * 3072 + 2048 + x];
        }
        __syncthreads();
        int tx = by * 32 + lx;
#pragma unroll
        for (int i = 0; i < 4; i++) {
            int ty = bx * 32 + ly8 + i * 8;
            v_t[(size_t)bz * 1024 * 2048 + (size_t)ty * 2048 + tx] = tile[lx][ly8 + i * 8];
        }
    } else {  // gates: 4 rows per block, 64 lanes per row
        unsigned bb = b - 8192u;
        int lane = t & 63;
        int row = bb * 4 + (t >> 6);
        const unsigned short* qr = C3 + (size_t)row * 3072 + lane * 16;
        uint4 a0 = *reinterpret_cast<const uint4*>(qr);
        uint4 a1 = *reinterpret_cast<const uint4*>(qr + 8);
        const float* wp = wg + lane * 16;
        float s = 0.f;
        unsigned ua[8] = {a0.x, a0.y, a0.z, a0.w, a1.x, a1.y, a1.z, a1.w};
#pragma unroll
        for (int j = 0; j < 8; j++) {
            s += bf2f((unsigned short)(ua[j] & 0xffff)) * wp[2 * j];
            s += bf2f((unsigned short)(ua[j] >> 16)) * wp[2 * j + 1];
        }
#pragma unroll
        for (int o = 1; o < 64; o <<= 1) s += __shfl_xor(s, o);
        if (lane == 0) gates[row] = 1.f / (1.f + __expf(-s));
    }
}

// ---------------- row softmax: f32 [8192][2048] -> bf16 probs ----------------
__global__ __launch_bounds__(256) void k_softmax(const float* __restrict__ logits,
                                                 unsigned short* __restrict__ probs) {
    __shared__ float red[8];
    size_t base = (size_t)blockIdx.x * 2048;
    const float4* src = reinterpret_cast<const float4*>(logits + base);
    int t = threadIdx.x;
    int wave = t >> 6, lane = t & 63;
    float4 v0 = src[t], v1 = src[t + 256];
    float m = fmaxf(fmaxf(fmaxf(v0.x, v0.y), fmaxf(v0.z, v0.w)),
                    fmaxf(fmaxf(v1.x, v1.y), fmaxf(v1.z, v1.w)));
#pragma unroll
    for (int o = 1; o < 64; o <<= 1) m = fmaxf(m, __shfl_xor(m, o));
    if (lane == 0) red[wave] = m;
    __syncthreads();
    m = fmaxf(fmaxf(red[0], red[1]), fmaxf(red[2], red[3]));
    float e[8];
    e[0] = __expf(v0.x - m); e[1] = __expf(v0.y - m);
    e[2] = __expf(v0.z - m); e[3] = __expf(v0.w - m);
    e[4] = __expf(v1.x - m); e[5] = __expf(v1.y - m);
    e[6] = __expf(v1.z - m); e[7] = __expf(v1.w - m);
    float s = e[0] + e[1] + e[2] + e[3] + e[4] + e[5] + e[6] + e[7];
#pragma unroll
    for (int o = 1; o < 64; o <<= 1) s += __shfl_xor(s, o);
    if (lane == 0) red[4 + wave] = s;
    __syncthreads();
    s = red[4] + red[5] + red[6] + red[7];
    float inv = 1.f / s;
    union { unsigned short u[4]; uint2 q; } o0, o1;
#pragma unroll
    for (int j = 0; j < 4; j++) o0.u[j] = f2bf(e[j] * inv);
#pragma unroll
    for (int j = 0; j < 4; j++) o1.u[j] = f2bf(e[4 + j] * inv);
    reinterpret_cast<uint2*>(probs + base)[t] = o0.q;
    reinterpret_cast<uint2*>(probs + base)[t + 256] = o1.q;
}

// ================= 8-phase 256-row GEMM: C[M,N] = A[M,K] @ Bt[N,K]^T =================
// BM=256, BK=64, 512 threads (8 waves). BN=256: MP=2 -> 16 MFMA/phase;
// BN=128: MP=1 -> 8 MFMA/phase. B-frags read once per K-tile (first phase),
// A staged 1 tile ahead, B 2 tiles ahead, counted vmcnt at ph4/ph8 only.
// XOR swizzle both-sides. yf: 0 = xT-fastest XCD chunks (share A-panel; use when
// B is small/L2-resident), 1 = yT-fastest (share B-panel; use when B-panel set
// would thrash the 4MB per-XCD L2).
template <int BN>
struct Geo {
    static constexpr int WN = BN / 64;
    static constexpr int WM = 8 / WN;
    static constexpr int WROWS = 256 / WM;
    static constexpr int MF = WROWS / 16;
    static constexpr int MP = MF / 4;
    static constexpr int ASZ = 256 * 64 * 2;
    static constexpr int BSZ = BN * 64 * 2;
    static constexpr int BUFSZ = ASZ + BSZ;
};

#define GPH(BUFOFF, MB, LB, STG, VMW)                                                   \
    {                                                                                   \
        const char* aB = smem + (BUFOFF);                                               \
        const char* bB = aB + G::ASZ;                                                   \
        bf16x8 af[G::MP * 2];                                                           \
        _Pragma("unroll") for (int mm = 0; mm < G::MP; ++mm)                            \
        _Pragma("unroll") for (int kk = 0; kk < 2; ++kk) {                              \
            int rowx = wrow + ((MB) + mm) * 16 + fr;                                    \
            int slot = (kk * 4 + kq) ^ (rowx & 7);                                      \
            af[mm * 2 + kk] = *reinterpret_cast<const bf16x8*>(aB + rowx * 128 + slot * 16); \
        }                                                                               \
        if (LB) {                                                                       \
            _Pragma("unroll") for (int nn = 0; nn < 4; ++nn)                            \
            _Pragma("unroll") for (int kk = 0; kk < 2; ++kk) {                          \
                int rowx = wcol + nn * 16 + fr;                                         \
                int slot = (kk * 4 + kq) ^ (rowx & 7);                                  \
                bfrag[nn * 2 + kk] = *reinterpret_cast<const bf16x8*>(bB + rowx * 128 + slot * 16); \
            }                                                                           \
        }                                                                               \
        STG;                                                                            \
        __builtin_amdgcn_sched_barrier(0);                                              \
        VMW;                                                                            \
        __builtin_amdgcn_s_barrier();                                                   \
        asm volatile("s_waitcnt lgkmcnt(0)" ::: "memory");                              \
        __builtin_amdgcn_sched_barrier(0);                                              \
        __builtin_amdgcn_s_setprio(1);                                                  \
        _Pragma("unroll") for (int mm = 0; mm < G::MP; ++mm)                            \
        _Pragma("unroll") for (int nn = 0; nn < 4; ++nn)                                \
        _Pragma("unroll") for (int kk = 0; kk < 2; ++kk)                                \
            acc[(MB) + mm][nn] = __builtin_amdgcn_mfma_f32_16x16x32_bf16(               \
                af[mm * 2 + kk], bfrag[nn * 2 + kk], acc[(MB) + mm][nn], 0, 0, 0);      \
        __builtin_amdgcn_s_setprio(0);                                                  \
        __builtin_amdgcn_sched_barrier(0);                                              \
        __builtin_amdgcn_s_barrier();                                                   \
        __builtin_amdgcn_sched_barrier(0);                                              \
    }

template <int EPI, int BN>
__global__ __launch_bounds__(512, 2) void k_gemm8(
    const unsigned short* __restrict__ A, int ldA, long long bsA,
    const unsigned short* __restrict__ Bt, int ldB, long long bsB,
    void* __restrict__ Cv, int ldC, long long bsC,
    const unsigned short* __restrict__ Qm, int ldQ,
    const float* __restrict__ gates, float alpha, int K,
    int NX, int NY, int NB, int yf) {
    using G = Geo<BN>;
    extern __shared__ char smem[];
    const int NT = K >> 6, NI = K >> 7;

    // bijective XCD swizzle (grid is always a multiple of 8)
    unsigned b = blockIdx.x;
    unsigned wg = (b & 7) * (gridDim.x >> 3) + (b >> 3);
    int xT, yT, zB;
    if (yf) {
        yT = wg % NY; unsigned r2 = wg / NY;
        xT = r2 % NX; zB = (int)(r2 / NX) % NB;
    } else {
        xT = wg % NX; unsigned r2 = wg / NX;
        yT = r2 % NY; zB = (int)(r2 / NY) % NB;
    }

    const unsigned short* Ab = A + (size_t)zB * (size_t)bsA;
    const unsigned short* Bb = Bt + (size_t)zB * (size_t)bsB;

    int t = threadIdx.x, lane = t & 63, wave = t >> 6;
    int wc = wave % G::WN, wr = wave / G::WN;
    int fr = lane & 15, kq = lane >> 4;
    int wrow = wr * G::WROWS, wcol = wc * 64;
    int trow = t >> 3, csx = (t & 7) ^ (trow & 7);
    long long rowTile = (long long)yT * 256, colTile = (long long)xT * BN;

    f32x4 acc[G::MF][4];
#pragma unroll
    for (int m = 0; m < G::MF; ++m)
#pragma unroll
        for (int n = 0; n < 4; ++n) acc[m][n] = (f32x4){0.f, 0.f, 0.f, 0.f};
    bf16x8 bfrag[8];

    auto stageA = [&](int buf, int h, int tt) {
        int kt = tt < NT ? tt : NT - 1;
#pragma unroll
        for (int rr = 0; rr < 2; ++rr) {
            const unsigned short* src =
                Ab + (size_t)(rowTile + h * 128 + rr * 64 + trow) * (size_t)ldA + kt * 64 + csx * 8;
            gload16(src, smem + buf * G::BUFSZ + h * 16384 + rr * 8192 + t * 16);
        }
    };
    auto stageB = [&](int buf, int h, int tt) {
        int kt = tt < NT ? tt : NT - 1;
        if (BN == 256) {
#pragma unroll
            for (int rr = 0; rr < 2; ++rr) {
                const unsigned short* src =
                    Bb + (size_t)(colTile + h * 128 + rr * 64 + trow) * (size_t)ldB + kt * 64 + csx * 8;
                gload16(src, smem + buf * G::BUFSZ + G::ASZ + h * 16384 + rr * 8192 + t * 16);
            }
        } else {
            const unsigned short* src =
                Bb + (size_t)(colTile + h * 64 + trow) * (size_t)ldB + kt * 64 + csx * 8;
            gload16(src, smem + buf * G::BUFSZ + G::ASZ + h * 8192 + t * 16);
        }
    };

    // prologue: tile0 full + tile1 B, drain all
    stageA(0, 0, 0); stageA(0, 1, 0);
    stageB(0, 0, 0); stageB(0, 1, 0);
    stageB(1, 0, 1); stageB(1, 1, 1);
    __builtin_amdgcn_sched_barrier(0);
    vm_wait<0>();
    __builtin_amdgcn_s_barrier();
    __builtin_amdgcn_sched_barrier(0);

    constexpr int VMN = (BN == 256) ? 4 : 2;
    for (int i = 0; i < NI; ++i) {
        int t1 = 2 * i + 1, t2 = 2 * i + 2, t3 = 2 * i + 3;
        GPH(0,          0,         1, stageA(1, 0, t1), (void)0);
        GPH(0,          G::MP,     0, stageA(1, 1, t1), (void)0);
        GPH(0,          2 * G::MP, 0, stageB(0, 0, t2), (void)0);
        GPH(0,          3 * G::MP, 0, stageB(0, 1, t2), vm_wait<VMN>());
        GPH(G::BUFSZ,   0,         1, stageA(0, 0, t2), (void)0);
        GPH(G::BUFSZ,   G::MP,     0, stageA(0, 1, t2), (void)0);
        GPH(G::BUFSZ,   2 * G::MP, 0, stageB(1, 0, t3), (void)0);
        GPH(G::BUFSZ,   3 * G::MP, 0, stageB(1, 1, t3), vm_wait<VMN>());
    }
    vm_wait<0>();

    // epilogue
    long long rb0 = rowTile + wrow + kq * 4;
    long long cb0 = colTile + wcol + fr;
    if (EPI == 0) {
        unsigned short* C = (unsigned short*)Cv + (size_t)zB * (size_t)bsC;
#pragma unroll
        for (int m = 0; m < G::MF; ++m)
#pragma unroll
            for (int n = 0; n < 4; ++n)
#pragma unroll
                for (int r = 0; r < 4; ++r)
                    C[(size_t)(rb0 + m * 16 + r) * (size_t)ldC + cb0 + n * 16] =
                        f2bf(acc[m][n][r] * alpha);
    } else if (EPI == 1) {
        unsigned short* C = (unsigned short*)Cv;
#pragma unroll
        for (int m = 0; m < G::MF; ++m)
#pragma unroll
            for (int r = 0; r < 4; ++r) {
                long long row = rb0 + m * 16 + r;
                float g = gates[row];
#pragma unroll
                for (int n = 0; n < 4; ++n) {
                    long long col = cb0 + n * 16;
                    float v = (bf2f(Qm[(size_t)row * (size_t)ldQ + col]) + g * acc[m][n][r]) * alpha;
                    C[(size_t)row * (size_t)ldC + col] = f2bf(v);
                }
            }
    } else {
        float* C = (float*)Cv + (size_t)zB * (size_t)bsC;
#pragma unroll
        for (int m = 0; m < G::MF; ++m)
#pragma unroll
            for (int n = 0; n < 4; ++n)
#pragma unroll
                for (int r = 0; r < 4; ++r)
                    C[(size_t)(rb0 + m * 16 + r) * (size_t)ldC + cb0 + n * 16] =
                        acc[m][n][r] * alpha;
    }
}

extern "C" void kernel_launch(void* const* d_in, const int* in_sizes, int n_in,
                              void* d_out, int out_size, void* d_ws, size_t ws_size,
                              hipStream_t stream) {
    const float* hs = (const float*)d_in[0];
    const float* pa = (const float*)d_in[1];
    const float* Wq = (const float*)d_in[2];
    const float* Wk = (const float*)d_in[3];
    const float* Wv = (const float*)d_in[4];
    const float* Wm = (const float*)d_in[5];
    const float* wg = (const float*)d_in[6];
    float* out = (float*)d_out;

    const int B = 4, S = 2048, H = 1024;
    const size_t BS = (size_t)B * S;
    const size_t BSH = BS * H;
    const size_t BSS = (size_t)B * S * S;
    const float inv_sqrt_h = 0.03125f;
    const float decay = 0.60653065971263342f;  // exp(-0.5)

    char* ws = (char*)d_ws;
    size_t off = 0;
    auto take = [&](size_t bytes) {
        char* p = ws + off;
        off += (bytes + 255) & ~(size_t)255;
        return p;
    };
    unsigned short* hs_bf = (unsigned short*)take(BSH * 2);           // reused as u_bf
    unsigned short* WT    = (unsigned short*)take(4ull * H * H * 2);  // [Wq^T;Wk^T;Wv^T;Wm^T]
    float* gates          = (float*)take(BS * 4);
    unsigned short* C3    = (unsigned short*)take(BS * 3 * H * 2);    // q|k|v [8192][3072]
    unsigned short* v_t   = (unsigned short*)take(BSH * 2);           // [B][1024][2048]
    unsigned short* pa_bf = (unsigned short*)take(BSS * 2);           // reused as probs
    float* logits         = (float*)take(BSS * 4);
    unsigned short* mv    = (unsigned short*)d_out;  // scratch: dead before final write
    unsigned short* u_bf  = hs_bf;
    unsigned short* probs = pa_bf;
    unsigned short* WmT   = WT + 3ull * H * H;

    (void)hipFuncSetAttribute((const void*)k_gemm8<0, 128>, hipFuncAttributeMaxDynamicSharedMemorySize, 98304);
    (void)hipFuncSetAttribute((const void*)k_gemm8<1, 128>, hipFuncAttributeMaxDynamicSharedMemorySize, 98304);
    (void)hipFuncSetAttribute((const void*)k_gemm8<2, 128>, hipFuncAttributeMaxDynamicSharedMemorySize, 98304);
    (void)hipFuncSetAttribute((const void*)k_gemm8<2, 256>, hipFuncAttributeMaxDynamicSharedMemorySize, 131072);

    // 1) prep: pa->bf16*decay, hs->bf16, W transposes (fused)
    k_prep<<<dim3(28672), 256, 0, stream>>>(hs, pa, Wq, Wk, Wv, Wm, hs_bf, pa_bf, WT, decay);
    // 2) QKV merged: C3 = hs_bf @ [Wq|Wk|Wv]  (BN=128, grid 24x32=768, B L2-resident -> xf)
    k_gemm8<0, 128><<<768, 512, 98304, stream>>>(
        hs_bf, H, 0, WT, H, 0, C3, 3 * H, 0, nullptr, 0, nullptr, 1.f, H, 24, 32, 1, 0);
    // 3) post: v^T + gates = sigmoid(q . w_gate)  (fused)
    k_post<<<dim3(10240), 256, 0, stream>>>(C3, v_t, wg, gates);
    // 4) mv = (pa*decay) @ v  [batched]  (BN=128, grid 8x8x4=256, yf=1: share B-panel)
    k_gemm8<0, 128><<<256, 512, 98304, stream>>>(
        pa_bf, S, (long long)S * S, v_t, S, (long long)H * S, mv, H, (long long)S * H,
        nullptr, 0, nullptr, 1.f, S, 8, 8, 4, 1);
    // 5) u = (q + gates * (mv @ Wm)) * inv_sqrt_h  (BN=128, grid 8x32=256, B small -> xf)
    k_gemm8<1, 128><<<256, 512, 98304, stream>>>(
        mv, H, 0, WmT, H, 0, u_bf, H, 0, C3, 3 * H, gates, inv_sqrt_h, H, 8, 32, 1, 0);
    // 6) logits = u @ k^T  [batched]  (BN=256, grid 8x8x4=256, yf=1)
    k_gemm8<2, 256><<<256, 512, 131072, stream>>>(
        u_bf, H, (long long)S * H, C3 + H, 3 * H, (long long)S * 3 * H,
        logits, S, (long long)S * S, nullptr, 0, nullptr, 1.f, H, 8, 8, 4, 1);
    // 7) softmax rows
    k_softmax<<<dim3((unsigned)BS), 256, 0, stream>>>(logits, probs);
    // 8) context = probs @ v  [batched]  (BN=128, grid 8x8x4=256, yf=1) -> d_out f32
    k_gemm8<2, 128><<<256, 512, 98304, stream>>>(
        probs, S, (long long)S * S, v_t, S, (long long)H * S, out, H, (long long)S * H,
        nullptr, 0, nullptr, 1.f, S, 8, 8, 4, 1);
}